// Round 4
// baseline (467.978 us; speedup 1.0000x reference)
//
#include <hip/hip_runtime.h>

// ---------- types ----------
typedef __attribute__((ext_vector_type(8))) __bf16 bf16x8;
typedef __attribute__((ext_vector_type(8))) unsigned short us8;
typedef __attribute__((ext_vector_type(4))) float f32x4;

#define DEV __device__ __forceinline__

DEV unsigned short f2bf(float f) {
    unsigned u = __builtin_bit_cast(unsigned, f);
    u += 0x7fffu + ((u >> 16) & 1u);
    return (unsigned short)(u >> 16);
}
DEV float bf2f(unsigned short h) {
    return __builtin_bit_cast(float, (unsigned)h << 16);
}

DEV void gload_lds16(const void* g, void* l) {
    __builtin_amdgcn_global_load_lds(
        (const __attribute__((address_space(1))) unsigned int*)g,
        (__attribute__((address_space(3))) unsigned int*)l, 16, 0, 0);
}

#define VMCNT8 asm volatile("s_waitcnt vmcnt(8)" ::: "memory")
#define VMCNT4 asm volatile("s_waitcnt vmcnt(4)" ::: "memory")
#define VMCNT0 asm volatile("s_waitcnt vmcnt(0)" ::: "memory")
#define BAR __builtin_amdgcn_s_barrier()
#define LGKM0                                          \
    asm volatile("s_waitcnt lgkmcnt(0)" ::: "memory"); \
    __builtin_amdgcn_sched_barrier(0)

// ---------- 256x256 fine-pipelined GEMM: C[M,N] = A[M,Ks] * B[N,Ks]^T ----------
// bf16 in, fp32 acc. EPI 0: bf16 store; 1: fp32 store (per-z partial); 2: relu(x+bias) bf16.
// 8 waves (2M x 4N), per-wave 128x64 output. BK=32, 4-buffer LDS rotation (4x32K=128K).
// Pipeline: compute tile kt from buf[kt&3]; stage tile kt+3 into buf[(kt+3)&3]
// split 2+2 gloads across the 2 phases (fine ds_read||G-load||MFMA interleave, m196).
// Per-wave ledger: 4 gloads/tile, 3 tiles in flight; vmcnt(8) at top retires tile kt
// (issued 3 tiles earlier). WAR: buf[(kt+3)&3]==buf[(kt-1)&3], reads done pre-barrier.
// Swizzle (64B rows, 4x16B slots): slot' = g ^ ((r>>1)&3); inverse on global src col.
template <int EPI>
__global__ __launch_bounds__(512) void gemm256(
    const unsigned short* __restrict__ A, const unsigned short* __restrict__ B,
    void* __restrict__ Cv, const float* __restrict__ bias,
    int lda, int ldb, int N, int Kslice) {
    extern __shared__ char smem[];  // 4 bufs x [A 16K | B 16K]
    const int t = threadIdx.x;

    // XCD-chunked bijective block swizzle (all grid totals divisible by 8)
    const int gx = gridDim.x, gy = gridDim.y;
    const int total = gx * gy * gridDim.z;
    int flat = blockIdx.x + gx * (blockIdx.y + gy * blockIdx.z);
    flat = (flat & 7) * (total >> 3) + (flat >> 3);
    const int bx = flat % gx;
    const int byz = flat / gx;
    const int by = byz % gy;
    const int z = byz / gy;

    const int m0 = by * 256, n0 = bx * 256;
    const unsigned short* Ag = A + (size_t)z * Kslice;
    const unsigned short* Bg = B + (size_t)z * Kslice;
    const int NT = Kslice >> 5;  // BK=32

    // staging precompute: 2 A-chunks + 2 B-chunks per thread per tile (16B each)
    size_t aoff[2], boff[2];
    int loff[2];
#pragma unroll
    for (int j = 0; j < 2; ++j) {
        int cj = j * 512 + t;
        int row = cj >> 2, slot = cj & 3;
        int col = (slot ^ ((row >> 1) & 3)) << 3;  // inverse-swizzled source col (elems)
        aoff[j] = (size_t)(m0 + row) * lda + col;
        boff[j] = (size_t)(n0 + row) * ldb + col;
        loff[j] = cj << 4;  // linear LDS byte offset
    }

    // fragment read precompute
    const int lane = t & 63, r = lane & 15, g = lane >> 4;
    const int wid = t >> 6, wm = wid >> 2, wn = wid & 3;
    const int s0 = (g ^ ((r >> 1) & 3)) << 4;  // swizzled 16B slot
    const int aRowB = (wm * 128 + r) * 64 + s0;
    const int bRowB = 16384 + (wn * 64 + r) * 64 + s0;

#define LDA8(buf, mi) (*(const bf16x8*)((buf) + aRowB + (mi) * 1024))
#define LDB8(buf, ni) (*(const bf16x8*)((buf) + bRowB + (ni) * 1024))
#define STAGE_A(buf, kt)                                                  \
    do {                                                                  \
        _Pragma("unroll") for (int j = 0; j < 2; ++j)                     \
            gload_lds16(Ag + aoff[j] + (size_t)(kt) * 32, (buf) + loff[j]); \
    } while (0)
#define STAGE_B(buf, kt)                                                  \
    do {                                                                  \
        _Pragma("unroll") for (int j = 0; j < 2; ++j)                     \
            gload_lds16(Bg + boff[j] + (size_t)(kt) * 32,                 \
                        (buf) + 16384 + loff[j]);                         \
    } while (0)

    f32x4 acc[8][4] = {};

    // prologue: stage tiles 0,1,2 (12 loads in flight)
    STAGE_A(smem, 0);
    STAGE_B(smem, 0);
    STAGE_A(smem + 32768, 1);
    STAGE_B(smem + 32768, 1);
    STAGE_A(smem + 65536, 2);
    STAGE_B(smem + 65536, 2);

    for (int kt = 0; kt < NT; ++kt) {
        // retire exactly tile kt's 4 loads (leave newer tiles in flight)
        if (kt < NT - 2) {
            VMCNT8;
        } else if (kt == NT - 2) {
            VMCNT4;
        } else {
            VMCNT0;
        }
        BAR;  // all waves' loads for tile kt have landed; prior buf reads retired
        char* buf = smem + (kt & 3) * 32768;
        char* nbuf = smem + ((kt + 3) & 3) * 32768;
        const bool st = (kt + 3) < NT;
        bf16x8 bfr[4], af[4];
        // ---- phase 0: 8 ds_reads + 2 gloads + 16 MFMA ----
#pragma unroll
        for (int ni = 0; ni < 4; ++ni) bfr[ni] = LDB8(buf, ni);
#pragma unroll
        for (int q = 0; q < 4; ++q) af[q] = LDA8(buf, q);
        if (st) STAGE_A(nbuf, kt + 3);
        BAR;
        LGKM0;
        __builtin_amdgcn_s_setprio(1);
#pragma unroll
        for (int q = 0; q < 4; ++q)
#pragma unroll
            for (int ni = 0; ni < 4; ++ni)
                acc[q][ni] = __builtin_amdgcn_mfma_f32_16x16x32_bf16(
                    af[q], bfr[ni], acc[q][ni], 0, 0, 0);
        __builtin_amdgcn_s_setprio(0);
        // ---- phase 1: 4 ds_reads + 2 gloads + 16 MFMA ----
#pragma unroll
        for (int q = 0; q < 4; ++q) af[q] = LDA8(buf, 4 + q);
        if (st) STAGE_B(nbuf, kt + 3);
        BAR;
        LGKM0;
        __builtin_amdgcn_s_setprio(1);
#pragma unroll
        for (int q = 0; q < 4; ++q)
#pragma unroll
            for (int ni = 0; ni < 4; ++ni)
                acc[4 + q][ni] = __builtin_amdgcn_mfma_f32_16x16x32_bf16(
                    af[q], bfr[ni], acc[4 + q][ni], 0, 0, 0);
        __builtin_amdgcn_s_setprio(0);
    }

    // epilogue: C-layout col=lane&15, row=(lane>>4)*4+j (verified mapping)
    const int crow0 = m0 + wm * 128 + g * 4;
    const int ccol0 = n0 + wn * 64 + r;
    float* Cp = (float*)Cv + (size_t)gridDim.y * 256 * N * z;
#pragma unroll
    for (int mi = 0; mi < 8; ++mi) {
#pragma unroll
        for (int ni = 0; ni < 4; ++ni) {
            int col = ccol0 + ni * 16;
            float bval = (EPI == 2) ? bias[col] : 0.f;
#pragma unroll
            for (int j = 0; j < 4; ++j) {
                int row = crow0 + mi * 16 + j;
                float v = acc[mi][ni][j];
                if (EPI == 0) {
                    ((unsigned short*)Cv)[(size_t)row * N + col] = f2bf(v);
                } else if (EPI == 1) {
                    Cp[(size_t)row * N + col] = v;
                } else {
                    v = fmaxf(v + bval, 0.f);
                    ((unsigned short*)Cv)[(size_t)row * N + col] = f2bf(v);
                }
            }
        }
    }
#undef LDA8
#undef LDB8
#undef STAGE_A
#undef STAGE_B
}

// ---------- fp32 -> bf16 convert ----------
__global__ __launch_bounds__(256) void cvt_kernel(
    const float* __restrict__ in, unsigned short* __restrict__ out, int n4) {
    int idx = blockIdx.x * 256 + threadIdx.x;
    if (idx >= n4) return;
    float4 v = *(const float4*)(in + (size_t)idx * 4);
    ushort4 u = make_ushort4(f2bf(v.x), f2bf(v.y), f2bf(v.z), f2bf(v.w));
    *(ushort4*)(out + (size_t)idx * 4) = u;
}

// ---------- energy[n,s,p=i*16+j] = (1/8) * dot64(Q[n,s,i], K[n,s,j]) ----------
__global__ __launch_bounds__(256) void energy_kernel(
    const unsigned short* __restrict__ QKV, float* __restrict__ E) {
    __shared__ __attribute__((aligned(16))) unsigned short Qs[8 * 1024];
    __shared__ __attribute__((aligned(16))) unsigned short Ks[8 * 1024];
    const int tid = threadIdx.x;
    const int n = blockIdx.y;
    const int s0 = blockIdx.x * 8;
#pragma unroll
    for (int c = 0; c < 4; ++c) {
        int e = c * 2048 + tid * 8;
        int row = e >> 10, col = e & 1023;
        int jj = col >> 6, db = (col >> 3) & 7;
        int sw = jj * 64 + (((db + jj) & 7) << 3);
        size_t gbase = (size_t)(n * 2048 + s0 + row) * 3072;
        *(us8*)(Qs + row * 1024 + sw) = *(const us8*)(QKV + gbase + col);
        *(us8*)(Ks + row * 1024 + sw) = *(const us8*)(QKV + gbase + 1024 + col);
    }
    __syncthreads();
    const int i = tid >> 4, j = tid & 15;
#pragma unroll
    for (int s = 0; s < 8; ++s) {
        float acc = 0.f;
#pragma unroll
        for (int d8 = 0; d8 < 8; ++d8) {
            us8 q = *(const us8*)(Qs + s * 1024 + i * 64 + (((d8 + i) & 7) << 3));
            us8 k = *(const us8*)(Ks + s * 1024 + j * 64 + (((d8 + j) & 7) << 3));
#pragma unroll
            for (int t = 0; t < 8; ++t) acc += bf2f(q[t]) * bf2f(k[t]);
        }
        E[(size_t)(n * 2048 + s0 + s) * 256 + tid] = acc * 0.125f;
    }
}

// ---------- softmax-over-s stats ----------
__global__ __launch_bounds__(256) void smax_part(
    const float* __restrict__ E, float* __restrict__ Mp, float* __restrict__ Zp) {
    const int p = threadIdx.x, n = blockIdx.y, sc = blockIdx.x;
    float m = -1e30f, z = 0.f;
    const float* base = E + ((size_t)n * 2048 + sc * 128) * 256 + p;
    for (int s = 0; s < 128; ++s) {
        float e = base[(size_t)s * 256];
        float mn = fmaxf(m, e);
        z = z * __expf(m - mn) + __expf(e - mn);
        m = mn;
    }
    int idx = (n * 16 + sc) * 256 + p;
    Mp[idx] = m;
    Zp[idx] = z;
}

__global__ __launch_bounds__(256) void smax_fin(
    const float* __restrict__ Mp, const float* __restrict__ Zp,
    float* __restrict__ Mf, float* __restrict__ RZf) {
    const int p = threadIdx.x, n = blockIdx.x;
    float m = -1e30f;
    for (int c = 0; c < 16; ++c) m = fmaxf(m, Mp[(n * 16 + c) * 256 + p]);
    float z = 0.f;
    for (int c = 0; c < 16; ++c)
        z += Zp[(n * 16 + c) * 256 + p] * __expf(Mp[(n * 16 + c) * 256 + p] - m);
    Mf[n * 256 + p] = m;
    RZf[n * 256 + p] = 1.f / z;
}

// ---------- attn_src[n, h*128+s/16, (s%16)*64+d] = A[n,h,s] * Vs[n,s,d] ----------
__global__ __launch_bounds__(256) void attnsrc_kernel(
    const unsigned short* __restrict__ QKV, const float* __restrict__ E,
    const float* __restrict__ Mf, const float* __restrict__ RZf,
    unsigned short* __restrict__ ASRC) {
    const int lane = threadIdx.x & 63;
    const int widx = blockIdx.x * 4 + (threadIdx.x >> 6);
    const int n = widx >> 11, s = widx & 2047;
    float vs = 0.f;
    const unsigned short* vrow = QKV + (size_t)(n * 2048 + s) * 3072 + 2048;
#pragma unroll
    for (int h = 0; h < 16; ++h) vs += bf2f(vrow[h * 64 + lane]);
    float aval = 0.f;
    if (lane < 16) {
        const float* erow = E + (size_t)(n * 2048 + s) * 256 + lane * 16;
        const float* mrow = Mf + n * 256 + lane * 16;
        const float* zrow = RZf + n * 256 + lane * 16;
#pragma unroll
        for (int j = 0; j < 16; ++j)
            aval += __expf(erow[j] - mrow[j]) * zrow[j];
    }
#pragma unroll
    for (int h = 0; h < 16; ++h) {
        float ah = __shfl(aval, h, 64);
        size_t row = (size_t)n * 2048 + h * 128 + (s >> 4);
        ASRC[row * 1024 + (s & 15) * 64 + lane] = f2bf(ah * vs);
    }
}

// ---------- LayerNorm(lin [+ lin2] + bias + resid) * w + b ----------
__global__ __launch_bounds__(256) void ln_kernel(
    const float* __restrict__ lin, const float* __restrict__ lin2,
    const float* __restrict__ bias, const float* __restrict__ resid,
    const float* __restrict__ w, const float* __restrict__ b,
    unsigned short* __restrict__ obf, float* __restrict__ of) {
    __shared__ float sm[16];
    const int row = blockIdx.x, c = threadIdx.x * 4;
    const size_t off = (size_t)row * 1024 + c;
    float4 v = *(const float4*)(lin + off);
    float4 bs = *(const float4*)(bias + c);
    float4 rx = *(const float4*)(resid + off);
    float t0 = v.x + bs.x + rx.x;
    float t1 = v.y + bs.y + rx.y;
    float t2 = v.z + bs.z + rx.z;
    float t3 = v.w + bs.w + rx.w;
    if (lin2) {
        float4 v2 = *(const float4*)(lin2 + off);
        t0 += v2.x; t1 += v2.y; t2 += v2.z; t3 += v2.w;
    }
    float s = t0 + t1 + t2 + t3;
    float ss = t0 * t0 + t1 * t1 + t2 * t2 + t3 * t3;
#pragma unroll
    for (int o = 32; o > 0; o >>= 1) {
        s += __shfl_down(s, o, 64);
        ss += __shfl_down(ss, o, 64);
    }
    const int wv = threadIdx.x >> 6, ln = threadIdx.x & 63;
    if (ln == 0) {
        sm[wv] = s;
        sm[8 + wv] = ss;
    }
    __syncthreads();
    if (threadIdx.x == 0) {
        sm[4] = sm[0] + sm[1] + sm[2] + sm[3];
        sm[12] = sm[8] + sm[9] + sm[10] + sm[11];
    }
    __syncthreads();
    s = sm[4];
    ss = sm[12];
    float mean = s * (1.f / 1024.f);
    float var = ss * (1.f / 1024.f) - mean * mean;
    float rstd = rsqrtf(var + 1e-5f);
    float4 wv4 = *(const float4*)(w + c);
    float4 bv4 = *(const float4*)(b + c);
    float o0 = (t0 - mean) * rstd * wv4.x + bv4.x;
    float o1 = (t1 - mean) * rstd * wv4.y + bv4.y;
    float o2 = (t2 - mean) * rstd * wv4.z + bv4.z;
    float o3 = (t3 - mean) * rstd * wv4.w + bv4.w;
    if (of) {
        float4 o = make_float4(o0, o1, o2, o3);
        *(float4*)(of + off) = o;
    }
    if (obf) {
        ushort4 u = make_ushort4(f2bf(o0), f2bf(o1), f2bf(o2), f2bf(o3));
        *(ushort4*)(obf + off) = u;
    }
}

// ---------- launch ----------
extern "C" void kernel_launch(void* const* d_in, const int* in_sizes, int n_in,
                              void* d_out, int out_size, void* d_ws, size_t ws_size,
                              hipStream_t stream) {
    const float* x = (const float*)d_in[0];
    const float* Wq = (const float*)d_in[1];
    const float* Wk = (const float*)d_in[2];
    const float* Wv = (const float*)d_in[3];
    const float* Wo = (const float*)d_in[4];
    const float* bo = (const float*)d_in[5];
    const float* ln1w = (const float*)d_in[6];
    const float* ln1b = (const float*)d_in[7];
    const float* ln2w = (const float*)d_in[8];
    const float* ln2b = (const float*)d_in[9];
    const float* W1 = (const float*)d_in[10];
    const float* bf1 = (const float*)d_in[11];
    const float* W2 = (const float*)d_in[12];
    const float* bf2 = (const float*)d_in[13];

    char* ws = (char*)d_ws;
    const size_t MB = 1u << 20;
    // region map (MB), lifetimes annotated:
    unsigned short* W1bf = (unsigned short*)(ws + 0);          // [1..8]
    unsigned short* W2bf = (unsigned short*)(ws + 8 * MB);     // [1..9]
    unsigned short* Wobf = (unsigned short*)(ws + 16 * MB);    // [1..6]
    unsigned short* Wqkvbf = (unsigned short*)(ws + 18 * MB);  // [1..2]
    float* Mp = (float*)(ws + 24 * MB);                        // [4]
    float* Zp = (float*)(ws + 24 * MB + 64 * 1024);            // [4]
    float* Mfin = (float*)(ws + 24 * MB + 128 * 1024);         // [4..5]
    float* RZfin = (float*)(ws + 24 * MB + 160 * 1024);        // [4..5]
    float* x1f = (float*)(ws + 16 * MB);                       // [7..10] (over Wobf/Wqkv/stats)
    unsigned short* ASRC = (unsigned short*)(ws + 48 * MB);    // [5..6]
    unsigned short* x1bf = (unsigned short*)(ws + 48 * MB);    // [7..8] (over ASRC)
    float* AL = (float*)(ws + 64 * MB);                        // [6..7] (z0:64-96, z1:96-128)
    unsigned short* H1 = (unsigned short*)(ws + 64 * MB);      // [8..9] (over AL)
    unsigned short* QKV = (unsigned short*)(ws + 128 * MB);    // [2..5]
    float* FF = (float*)(ws + 128 * MB);                       // [9..10] (over QKV/EN)
    unsigned short* xbf = (unsigned short*)(ws + 176 * MB);    // [1..2]
    float* EN = (float*)(ws + 176 * MB);                       // [3..5] (over xbf)

    // allow 128 KiB dynamic LDS (idempotent; safe under graph capture)
    auto k0 = gemm256<0>; auto k1 = gemm256<1>; auto k2 = gemm256<2>;
    (void)hipFuncSetAttribute((const void*)k0, hipFuncAttributeMaxDynamicSharedMemorySize, 131072);
    (void)hipFuncSetAttribute((const void*)k1, hipFuncAttributeMaxDynamicSharedMemorySize, 131072);
    (void)hipFuncSetAttribute((const void*)k2, hipFuncAttributeMaxDynamicSharedMemorySize, 131072);

    auto cvt = [&](const float* src, unsigned short* dst, int n) {
        int n4 = n >> 2;
        cvt_kernel<<<dim3((n4 + 255) / 256), dim3(256), 0, stream>>>(src, dst, n4);
    };
    cvt(x, xbf, 8192 * 1024);
    cvt(Wq, Wqkvbf, 1024 * 1024);
    cvt(Wk, Wqkvbf + 1024 * 1024, 1024 * 1024);
    cvt(Wv, Wqkvbf + 2 * 1024 * 1024, 1024 * 1024);
    cvt(Wo, Wobf, 1024 * 1024);
    cvt(W1, W1bf, 4096 * 1024);
    cvt(W2, W2bf, 4096 * 1024);

    // 2. QKV = xbf @ [Wq;Wk;Wv]^T  (8192 x 3072, bf16)
    gemm256<0><<<dim3(12, 32, 1), 512, 131072, stream>>>(
        xbf, Wqkvbf, QKV, nullptr, 1024, 1024, 3072, 1024);
    // 3-5. attention (cheap part)
    energy_kernel<<<dim3(256, 4), 256, 0, stream>>>(QKV, EN);
    smax_part<<<dim3(16, 4), 256, 0, stream>>>(EN, Mp, Zp);
    smax_fin<<<dim3(4), 256, 0, stream>>>(Mp, Zp, Mfin, RZfin);
    attnsrc_kernel<<<dim3(2048), 256, 0, stream>>>(QKV, EN, Mfin, RZfin, ASRC);
    // 6. attn_lin = ASRC @ Wo^T, split-K=2 fp32 partials
    gemm256<1><<<dim3(4, 32, 2), 512, 131072, stream>>>(
        ASRC, Wobf, AL, nullptr, 1024, 1024, 1024, 512);
    // 7. x1 = LN1(AL0 + AL1 + bo + x)
    ln_kernel<<<dim3(8192), 256, 0, stream>>>(
        AL, AL + (size_t)8192 * 1024, bo, x, ln1w, ln1b, x1bf, x1f);
    // 8. H1 = relu(x1 @ W1^T + bf1)
    gemm256<2><<<dim3(16, 32, 1), 512, 131072, stream>>>(
        x1bf, W1bf, H1, bf1, 1024, 1024, 4096, 1024);
    // 9. ff = H1 @ W2^T, split-K=2 fp32 partials
    gemm256<1><<<dim3(4, 32, 2), 512, 131072, stream>>>(
        H1, W2bf, FF, nullptr, 4096, 4096, 1024, 2048);
    // 10. out = LN2(ff0 + ff1 + bf2 + x1)
    ln_kernel<<<dim3(8192), 256, 0, stream>>>(
        FF, FF + (size_t)8192 * 1024, bf2, x1f, ln2w, ln2b, nullptr, (float*)d_out);
}

// Round 6
// 441.655 us; speedup vs baseline: 1.0596x; 1.0596x over previous
//
#include <hip/hip_runtime.h>

// ---------- types ----------
typedef __attribute__((ext_vector_type(8))) __bf16 bf16x8;
typedef __attribute__((ext_vector_type(8))) unsigned short us8;
typedef __attribute__((ext_vector_type(4))) float f32x4;

#define DEV __device__ __forceinline__

DEV unsigned short f2bf(float f) {
    unsigned u = __builtin_bit_cast(unsigned, f);
    u += 0x7fffu + ((u >> 16) & 1u);
    return (unsigned short)(u >> 16);
}
DEV float bf2f(unsigned short h) {
    return __builtin_bit_cast(float, (unsigned)h << 16);
}

DEV void gload_lds16(const void* g, void* l) {
    __builtin_amdgcn_global_load_lds(
        (const __attribute__((address_space(1))) unsigned int*)g,
        (__attribute__((address_space(3))) unsigned int*)l, 16, 0, 0);
}

#define VMCNT8 asm volatile("s_waitcnt vmcnt(8)" ::: "memory")
#define VMCNT4 asm volatile("s_waitcnt vmcnt(4)" ::: "memory")
#define VMCNT0 asm volatile("s_waitcnt vmcnt(0)" ::: "memory")
#define LGKM8 asm volatile("s_waitcnt lgkmcnt(8)" ::: "memory")
#define LGKM4 asm volatile("s_waitcnt lgkmcnt(4)" ::: "memory")
#define LGKM0 asm volatile("s_waitcnt lgkmcnt(0)" ::: "memory")
#define BAR __builtin_amdgcn_s_barrier()
#define SCHED0 __builtin_amdgcn_sched_barrier(0)

// ---------- 256x256 GEMM, counted-lgkm read-ahead pipeline ----------
// C[M,N] = A[M,Ks] * B[N,Ks]^T, bf16 in, fp32 acc.
// EPI 0: bf16 store; 1: fp32 store (per-z partial); 2: relu(x+bias) bf16.
// 8 waves (2M x 4N), per-wave 128x64. BK=32, 4-buffer LDS rotation (128K), 1 block/CU.
// Per tile (ONE barrier): vmcnt(4) retires tile kt+1's stage; BAR; read afH(kt);
// STAGE_A(kt+3); lgkm(4) -> MFMA-A overlapped with issue of kt+1's 8 reads (legal:
// kt+1 landed); STAGE_B(kt+3); lgkm(8) -> MFMA-B. LDS port serves next reads
// during MFMA (the m201 counted-lgkm mechanism). Registers ping-pong (rule #20).
template <int EPI>
__global__ __launch_bounds__(512) void gemm256(
    const unsigned short* __restrict__ A, const unsigned short* __restrict__ B,
    void* __restrict__ Cv, const float* __restrict__ bias,
    int lda, int ldb, int N, int Kslice) {
    extern __shared__ char smem[];  // 4 bufs x [A 16K | B 16K]
    const int t = threadIdx.x;

    // XCD-chunked bijective block swizzle (all grid totals divisible by 8)
    const int gx = gridDim.x, gy = gridDim.y;
    const int total = gx * gy * gridDim.z;
    int flat = blockIdx.x + gx * (blockIdx.y + gy * blockIdx.z);
    flat = (flat & 7) * (total >> 3) + (flat >> 3);
    const int bx = flat % gx;
    const int byz = flat / gx;
    const int by = byz % gy;
    const int z = byz / gy;

    const int m0 = by * 256, n0 = bx * 256;
    const unsigned short* Ag = A + (size_t)z * Kslice;
    const unsigned short* Bg = B + (size_t)z * Kslice;
    const int NT = Kslice >> 5;  // BK=32

    // staging precompute: 2 A-chunks + 2 B-chunks per thread per tile (16B each)
    size_t aoff[2], boff[2];
    int loff[2];
#pragma unroll
    for (int j = 0; j < 2; ++j) {
        int cj = j * 512 + t;
        int row = cj >> 2, slot = cj & 3;
        int col = (slot ^ ((row >> 1) & 3)) << 3;  // inverse-swizzled source col (elems)
        aoff[j] = (size_t)(m0 + row) * lda + col;
        boff[j] = (size_t)(n0 + row) * ldb + col;
        loff[j] = cj << 4;  // linear LDS byte offset
    }

    // fragment read precompute
    const int lane = t & 63, r = lane & 15, g = lane >> 4;
    const int wid = t >> 6, wm = wid >> 2, wn = wid & 3;
    const int s0 = (g ^ ((r >> 1) & 3)) << 4;  // swizzled 16B slot
    const int aRowB = (wm * 128 + r) * 64 + s0;
    const int bRowB = 16384 + (wn * 64 + r) * 64 + s0;

#define LDA8(buf, mi) (*(const bf16x8*)((buf) + aRowB + (mi) * 1024))
#define LDB8(buf, ni) (*(const bf16x8*)((buf) + bRowB + (ni) * 1024))
#define STAGE_A(buf, kt)                                                    \
    do {                                                                    \
        _Pragma("unroll") for (int j = 0; j < 2; ++j)                       \
            gload_lds16(Ag + aoff[j] + (size_t)(kt) * 32, (buf) + loff[j]); \
    } while (0)
#define STAGE_B(buf, kt)                                                    \
    do {                                                                    \
        _Pragma("unroll") for (int j = 0; j < 2; ++j)                       \
            gload_lds16(Bg + boff[j] + (size_t)(kt) * 32,                   \
                        (buf) + 16384 + loff[j]);                           \
    } while (0)

    f32x4 acc[8][4] = {};
    bf16x8 bfr0[4], afL0[4], bfr1[4], afL1[4], afH[4];

    // prologue: stage tiles 0,1,2 (12 loads); retire tile 0; preload tile-0 A-group
    STAGE_A(smem, 0);
    STAGE_B(smem, 0);
    STAGE_A(smem + 32768, 1);
    STAGE_B(smem + 32768, 1);
    STAGE_A(smem + 65536, 2);
    STAGE_B(smem + 65536, 2);
    VMCNT8;
    BAR;
#pragma unroll
    for (int ni = 0; ni < 4; ++ni) bfr0[ni] = LDB8(smem, ni);
#pragma unroll
    for (int q = 0; q < 4; ++q) afL0[q] = LDA8(smem, q);
    SCHED0;

// one K-tile step. CBFR/CAFL: current tile's A-group regs (already issued);
// NBFR/NAFL: regs for next tile's A-group (issued here, waited next step).
#define TILE_STEP(CBFR, CAFL, NBFR, NAFL, KT)                                 \
    do {                                                                      \
        const int _kt = (KT);                                                 \
        if (_kt >= NT - 2) { VMCNT0; } else { VMCNT4; }                       \
        BAR;                                                                  \
        char* _buf = smem + (_kt & 3) * 32768;                                \
        char* _sbuf = smem + ((_kt + 3) & 3) * 32768;                         \
        _Pragma("unroll") for (int q = 0; q < 4; ++q)                         \
            afH[q] = LDA8(_buf, 4 + q);                                       \
        SCHED0;                                                               \
        if (_kt + 3 < NT) STAGE_A(_sbuf, _kt + 3);                            \
        SCHED0;                                                               \
        LGKM4;                                                                \
        SCHED0;                                                               \
        __builtin_amdgcn_s_setprio(1);                                        \
        _Pragma("unroll") for (int q = 0; q < 4; ++q)                         \
            _Pragma("unroll") for (int ni = 0; ni < 4; ++ni)                  \
                acc[q][ni] = __builtin_amdgcn_mfma_f32_16x16x32_bf16(         \
                    CAFL[q], CBFR[ni], acc[q][ni], 0, 0, 0);                  \
        __builtin_amdgcn_s_setprio(0);                                        \
        SCHED0;                                                               \
        if (_kt + 1 < NT) {                                                   \
            char* _nb = smem + ((_kt + 1) & 3) * 32768;                       \
            _Pragma("unroll") for (int ni = 0; ni < 4; ++ni)                  \
                NBFR[ni] = LDB8(_nb, ni);                                     \
            _Pragma("unroll") for (int q = 0; q < 4; ++q)                     \
                NAFL[q] = LDA8(_nb, q);                                       \
        }                                                                     \
        SCHED0;                                                               \
        if (_kt + 3 < NT) STAGE_B(_sbuf, _kt + 3);                            \
        SCHED0;                                                               \
        if (_kt + 1 < NT) { LGKM8; } else { LGKM0; }                          \
        SCHED0;                                                               \
        __builtin_amdgcn_s_setprio(1);                                        \
        _Pragma("unroll") for (int q = 0; q < 4; ++q)                         \
            _Pragma("unroll") for (int ni = 0; ni < 4; ++ni)                  \
                acc[4 + q][ni] = __builtin_amdgcn_mfma_f32_16x16x32_bf16(     \
                    afH[q], CBFR[ni], acc[4 + q][ni], 0, 0, 0);               \
        __builtin_amdgcn_s_setprio(0);                                        \
    } while (0)

    for (int kt = 0; kt < NT; kt += 2) {
        TILE_STEP(bfr0, afL0, bfr1, afL1, kt);
        TILE_STEP(bfr1, afL1, bfr0, afL0, kt + 1);
    }

    // epilogue: C-layout col=lane&15, row=(lane>>4)*4+j (verified mapping)
    const int crow0 = m0 + wm * 128 + g * 4;
    const int ccol0 = n0 + wn * 64 + r;
    float* Cp = (float*)Cv + (size_t)gridDim.y * 256 * N * z;
#pragma unroll
    for (int mi = 0; mi < 8; ++mi) {
#pragma unroll
        for (int ni = 0; ni < 4; ++ni) {
            int col = ccol0 + ni * 16;
            float bval = (EPI == 2) ? bias[col] : 0.f;
#pragma unroll
            for (int j = 0; j < 4; ++j) {
                int row = crow0 + mi * 16 + j;
                float v = acc[mi][ni][j];
                if (EPI == 0) {
                    ((unsigned short*)Cv)[(size_t)row * N + col] = f2bf(v);
                } else if (EPI == 1) {
                    Cp[(size_t)row * N + col] = v;
                } else {
                    v = fmaxf(v + bval, 0.f);
                    ((unsigned short*)Cv)[(size_t)row * N + col] = f2bf(v);
                }
            }
        }
    }
#undef LDA8
#undef LDB8
#undef STAGE_A
#undef STAGE_B
#undef TILE_STEP
}

// ---------- fp32 -> bf16 convert ----------
__global__ __launch_bounds__(256) void cvt_kernel(
    const float* __restrict__ in, unsigned short* __restrict__ out, int n4) {
    int idx = blockIdx.x * 256 + threadIdx.x;
    if (idx >= n4) return;
    float4 v = *(const float4*)(in + (size_t)idx * 4);
    ushort4 u = make_ushort4(f2bf(v.x), f2bf(v.y), f2bf(v.z), f2bf(v.w));
    *(ushort4*)(out + (size_t)idx * 4) = u;
}

// ---------- energy[n,s,p=i*16+j] = (1/8) * dot64(Q[n,s,i], K[n,s,j]) ----------
__global__ __launch_bounds__(256) void energy_kernel(
    const unsigned short* __restrict__ QKV, float* __restrict__ E) {
    __shared__ __attribute__((aligned(16))) unsigned short Qs[8 * 1024];
    __shared__ __attribute__((aligned(16))) unsigned short Ks[8 * 1024];
    const int tid = threadIdx.x;
    const int n = blockIdx.y;
    const int s0 = blockIdx.x * 8;
#pragma unroll
    for (int c = 0; c < 4; ++c) {
        int e = c * 2048 + tid * 8;
        int row = e >> 10, col = e & 1023;
        int jj = col >> 6, db = (col >> 3) & 7;
        int sw = jj * 64 + (((db + jj) & 7) << 3);
        size_t gbase = (size_t)(n * 2048 + s0 + row) * 3072;
        *(us8*)(Qs + row * 1024 + sw) = *(const us8*)(QKV + gbase + col);
        *(us8*)(Ks + row * 1024 + sw) = *(const us8*)(QKV + gbase + 1024 + col);
    }
    __syncthreads();
    const int i = tid >> 4, j = tid & 15;
#pragma unroll
    for (int s = 0; s < 8; ++s) {
        float acc = 0.f;
#pragma unroll
        for (int d8 = 0; d8 < 8; ++d8) {
            us8 q = *(const us8*)(Qs + s * 1024 + i * 64 + (((d8 + i) & 7) << 3));
            us8 k = *(const us8*)(Ks + s * 1024 + j * 64 + (((d8 + j) & 7) << 3));
#pragma unroll
            for (int t = 0; t < 8; ++t) acc += bf2f(q[t]) * bf2f(k[t]);
        }
        E[(size_t)(n * 2048 + s0 + s) * 256 + tid] = acc * 0.125f;
    }
}

// ---------- softmax-over-s stats (32-row chunks, 256 blocks) ----------
__global__ __launch_bounds__(256) void smax_part(
    const float* __restrict__ E, float* __restrict__ Mp, float* __restrict__ Zp) {
    const int p = threadIdx.x, n = blockIdx.y, sc = blockIdx.x;
    float m = -1e30f, z = 0.f;
    const float* base = E + ((size_t)n * 2048 + sc * 32) * 256 + p;
    for (int s = 0; s < 32; ++s) {
        float e = base[(size_t)s * 256];
        float mn = fmaxf(m, e);
        z = z * __expf(m - mn) + __expf(e - mn);
        m = mn;
    }
    int idx = (n * 64 + sc) * 256 + p;
    Mp[idx] = m;
    Zp[idx] = z;
}

__global__ __launch_bounds__(256) void smax_fin(
    const float* __restrict__ Mp, const float* __restrict__ Zp,
    float* __restrict__ Mf, float* __restrict__ RZf) {
    const int p = threadIdx.x, n = blockIdx.x;
    float m = -1e30f;
    for (int c = 0; c < 64; ++c) m = fmaxf(m, Mp[(n * 64 + c) * 256 + p]);
    float z = 0.f;
    for (int c = 0; c < 64; ++c)
        z += Zp[(n * 64 + c) * 256 + p] * __expf(Mp[(n * 64 + c) * 256 + p] - m);
    Mf[n * 256 + p] = m;
    RZf[n * 256 + p] = 1.f / z;
}

// ---------- attn_src[n, h*128+s/16, (s%16)*64+d] = A[n,h,s] * Vs[n,s,d] ----------
__global__ __launch_bounds__(256) void attnsrc_kernel(
    const unsigned short* __restrict__ QKV, const float* __restrict__ E,
    const float* __restrict__ Mf, const float* __restrict__ RZf,
    unsigned short* __restrict__ ASRC) {
    const int lane = threadIdx.x & 63;
    const int widx = blockIdx.x * 4 + (threadIdx.x >> 6);
    const int n = widx >> 11, s = widx & 2047;
    float vs = 0.f;
    const unsigned short* vrow = QKV + (size_t)(n * 2048 + s) * 3072 + 2048;
#pragma unroll
    for (int h = 0; h < 16; ++h) vs += bf2f(vrow[h * 64 + lane]);
    float aval = 0.f;
    if (lane < 16) {
        const float* erow = E + (size_t)(n * 2048 + s) * 256 + lane * 16;
        const float* mrow = Mf + n * 256 + lane * 16;
        const float* zrow = RZf + n * 256 + lane * 16;
#pragma unroll
        for (int j = 0; j < 16; ++j)
            aval += __expf(erow[j] - mrow[j]) * zrow[j];
    }
#pragma unroll
    for (int h = 0; h < 16; ++h) {
        float ah = __shfl(aval, h, 64);
        size_t row = (size_t)n * 2048 + h * 128 + (s >> 4);
        ASRC[row * 1024 + (s & 15) * 64 + lane] = f2bf(ah * vs);
    }
}

// ---------- LayerNorm(lin [+ lin2] + bias + resid) * w + b ----------
__global__ __launch_bounds__(256) void ln_kernel(
    const float* __restrict__ lin, const float* __restrict__ lin2,
    const float* __restrict__ bias, const float* __restrict__ resid,
    const float* __restrict__ w, const float* __restrict__ b,
    unsigned short* __restrict__ obf, float* __restrict__ of) {
    __shared__ float sm[16];
    const int row = blockIdx.x, c = threadIdx.x * 4;
    const size_t off = (size_t)row * 1024 + c;
    float4 v = *(const float4*)(lin + off);
    float4 bs = *(const float4*)(bias + c);
    float4 rx = *(const float4*)(resid + off);
    float t0 = v.x + bs.x + rx.x;
    float t1 = v.y + bs.y + rx.y;
    float t2 = v.z + bs.z + rx.z;
    float t3 = v.w + bs.w + rx.w;
    if (lin2) {
        float4 v2 = *(const float4*)(lin2 + off);
        t0 += v2.x; t1 += v2.y; t2 += v2.z; t3 += v2.w;
    }
    float s = t0 + t1 + t2 + t3;
    float ss = t0 * t0 + t1 * t1 + t2 * t2 + t3 * t3;
#pragma unroll
    for (int o = 32; o > 0; o >>= 1) {
        s += __shfl_down(s, o, 64);
        ss += __shfl_down(ss, o, 64);
    }
    const int wv = threadIdx.x >> 6, ln = threadIdx.x & 63;
    if (ln == 0) {
        sm[wv] = s;
        sm[8 + wv] = ss;
    }
    __syncthreads();
    if (threadIdx.x == 0) {
        sm[4] = sm[0] + sm[1] + sm[2] + sm[3];
        sm[12] = sm[8] + sm[9] + sm[10] + sm[11];
    }
    __syncthreads();
    s = sm[4];
    ss = sm[12];
    float mean = s * (1.f / 1024.f);
    float var = ss * (1.f / 1024.f) - mean * mean;
    float rstd = rsqrtf(var + 1e-5f);
    float4 wv4 = *(const float4*)(w + c);
    float4 bv4 = *(const float4*)(b + c);
    float o0 = (t0 - mean) * rstd * wv4.x + bv4.x;
    float o1 = (t1 - mean) * rstd * wv4.y + bv4.y;
    float o2 = (t2 - mean) * rstd * wv4.z + bv4.z;
    float o3 = (t3 - mean) * rstd * wv4.w + bv4.w;
    if (of) {
        float4 o = make_float4(o0, o1, o2, o3);
        *(float4*)(of + off) = o;
    }
    if (obf) {
        ushort4 u = make_ushort4(f2bf(o0), f2bf(o1), f2bf(o2), f2bf(o3));
        *(ushort4*)(obf + off) = u;
    }
}

// ---------- launch ----------
extern "C" void kernel_launch(void* const* d_in, const int* in_sizes, int n_in,
                              void* d_out, int out_size, void* d_ws, size_t ws_size,
                              hipStream_t stream) {
    const float* x = (const float*)d_in[0];
    const float* Wq = (const float*)d_in[1];
    const float* Wk = (const float*)d_in[2];
    const float* Wv = (const float*)d_in[3];
    const float* Wo = (const float*)d_in[4];
    const float* bo = (const float*)d_in[5];
    const float* ln1w = (const float*)d_in[6];
    const float* ln1b = (const float*)d_in[7];
    const float* ln2w = (const float*)d_in[8];
    const float* ln2b = (const float*)d_in[9];
    const float* W1 = (const float*)d_in[10];
    const float* bf1 = (const float*)d_in[11];
    const float* W2 = (const float*)d_in[12];
    const float* bf2 = (const float*)d_in[13];

    char* ws = (char*)d_ws;
    const size_t MB = 1u << 20;
    const size_t KB = 1u << 10;
    // region map (MB), lifetimes annotated:
    unsigned short* W1bf = (unsigned short*)(ws + 0);          // [1..8]
    unsigned short* W2bf = (unsigned short*)(ws + 8 * MB);     // [1..9]
    unsigned short* Wobf = (unsigned short*)(ws + 16 * MB);    // [1..6]
    unsigned short* Wqkvbf = (unsigned short*)(ws + 18 * MB);  // [1..2]
    float* Mp = (float*)(ws + 24 * MB);                        // [4] 256KB
    float* Zp = (float*)(ws + 24 * MB + 256 * KB);             // [4] 256KB
    float* Mfin = (float*)(ws + 24 * MB + 512 * KB);           // [4..5]
    float* RZfin = (float*)(ws + 24 * MB + 528 * KB);          // [4..5]
    float* x1f = (float*)(ws + 16 * MB);                       // [7..10] (over Wobf/Wqkv/stats)
    unsigned short* ASRC = (unsigned short*)(ws + 48 * MB);    // [5..6]
    unsigned short* x1bf = (unsigned short*)(ws + 48 * MB);    // [7..8] (over ASRC)
    float* AL = (float*)(ws + 64 * MB);                        // [6..7] (z0:64-96, z1:96-128)
    unsigned short* H1 = (unsigned short*)(ws + 64 * MB);      // [8..9] (over AL)
    unsigned short* QKV = (unsigned short*)(ws + 128 * MB);    // [2..5]
    float* FF = (float*)(ws + 128 * MB);                       // [9..10] (over QKV/EN)
    unsigned short* xbf = (unsigned short*)(ws + 176 * MB);    // [1..2]
    float* EN = (float*)(ws + 176 * MB);                       // [3..5] (over xbf)

    // allow 128 KiB dynamic LDS (idempotent; safe under graph capture)
    auto k0 = gemm256<0>; auto k1 = gemm256<1>; auto k2 = gemm256<2>;
    (void)hipFuncSetAttribute((const void*)k0, hipFuncAttributeMaxDynamicSharedMemorySize, 131072);
    (void)hipFuncSetAttribute((const void*)k1, hipFuncAttributeMaxDynamicSharedMemorySize, 131072);
    (void)hipFuncSetAttribute((const void*)k2, hipFuncAttributeMaxDynamicSharedMemorySize, 131072);

    auto cvt = [&](const float* src, unsigned short* dst, int n) {
        int n4 = n >> 2;
        cvt_kernel<<<dim3((n4 + 255) / 256), dim3(256), 0, stream>>>(src, dst, n4);
    };
    cvt(x, xbf, 8192 * 1024);
    cvt(Wq, Wqkvbf, 1024 * 1024);
    cvt(Wk, Wqkvbf + 1024 * 1024, 1024 * 1024);
    cvt(Wv, Wqkvbf + 2 * 1024 * 1024, 1024 * 1024);
    cvt(Wo, Wobf, 1024 * 1024);
    cvt(W1, W1bf, 4096 * 1024);
    cvt(W2, W2bf, 4096 * 1024);

    // 2. QKV = xbf @ [Wq;Wk;Wv]^T  (8192 x 3072, bf16)
    gemm256<0><<<dim3(12, 32, 1), 512, 131072, stream>>>(
        xbf, Wqkvbf, QKV, nullptr, 1024, 1024, 3072, 1024);
    // 3-5. attention (cheap part)
    energy_kernel<<<dim3(256, 4), 256, 0, stream>>>(QKV, EN);
    smax_part<<<dim3(64, 4), 256, 0, stream>>>(EN, Mp, Zp);
    smax_fin<<<dim3(4), 256, 0, stream>>>(Mp, Zp, Mfin, RZfin);
    attnsrc_kernel<<<dim3(2048), 256, 0, stream>>>(QKV, EN, Mfin, RZfin, ASRC);
    // 6. attn_lin = ASRC @ Wo^T, split-K=2 fp32 partials
    gemm256<1><<<dim3(4, 32, 2), 512, 131072, stream>>>(
        ASRC, Wobf, AL, nullptr, 1024, 1024, 1024, 512);
    // 7. x1 = LN1(AL0 + AL1 + bo + x)
    ln_kernel<<<dim3(8192), 256, 0, stream>>>(
        AL, AL + (size_t)8192 * 1024, bo, x, ln1w, ln1b, x1bf, x1f);
    // 8. H1 = relu(x1 @ W1^T + bf1)
    gemm256<2><<<dim3(16, 32, 1), 512, 131072, stream>>>(
        x1bf, W1bf, H1, bf1, 1024, 1024, 4096, 1024);
    // 9. ff = H1 @ W2^T, split-K=2 fp32 partials
    gemm256<1><<<dim3(4, 32, 2), 512, 131072, stream>>>(
        H1, W2bf, FF, nullptr, 4096, 4096, 1024, 2048);
    // 10. out = LN2(ff0 + ff1 + bf2 + x1)
    ln_kernel<<<dim3(8192), 256, 0, stream>>>(
        FF, FF + (size_t)8192 * 1024, bf2, x1f, ln2w, ln2b, nullptr, (float*)d_out);
}

// Round 8
// 439.323 us; speedup vs baseline: 1.0652x; 1.0053x over previous
//
#include <hip/hip_runtime.h>

// ---------- types ----------
typedef __attribute__((ext_vector_type(8))) __bf16 bf16x8;
typedef __attribute__((ext_vector_type(8))) unsigned short us8;
typedef __attribute__((ext_vector_type(4))) float f32x4;

#define DEV __device__ __forceinline__

DEV unsigned short f2bf(float f) {
    unsigned u = __builtin_bit_cast(unsigned, f);
    u += 0x7fffu + ((u >> 16) & 1u);
    return (unsigned short)(u >> 16);
}
DEV float bf2f(unsigned short h) {
    return __builtin_bit_cast(float, (unsigned)h << 16);
}

DEV void gload_lds16(const void* g, void* l) {
    __builtin_amdgcn_global_load_lds(
        (const __attribute__((address_space(1))) unsigned int*)g,
        (__attribute__((address_space(3))) unsigned int*)l, 16, 0, 0);
}

#define VMCNT4 asm volatile("s_waitcnt vmcnt(4)" ::: "memory")
#define VMCNT0 asm volatile("s_waitcnt vmcnt(0)" ::: "memory")
#define LGKM0S                                         \
    asm volatile("s_waitcnt lgkmcnt(0)" ::: "memory"); \
    __builtin_amdgcn_sched_barrier(0)
#define BAR __builtin_amdgcn_s_barrier()
#define SCHED0 __builtin_amdgcn_sched_barrier(0)

// ---------- 256x256 8-phase GEMM (m201-faithful): C = A[M,Ks] * B[N,Ks]^T ----------
// bf16 in, fp32 acc. EPI 0: bf16; 1: fp32 (per-z partial); 2: relu(x+bias) bf16.
// 8 waves (2M x 4N), per-wave 128x64. BK=64, 2 dbuf x 64KB (A half0|half1|B half0|half1,
// 16KB each). 4 phases/tile, quadrant order (m0n0,m0n1,m1n0,m1n1): B-halves retire
// after P1, A-halves after P3. Stage rotation: P0->A0(t+1), P1->A1(t+1) [nd, safe],
// P2->B0(t+2), P3->B1(t+2) [cur; safe: cur B reads retired via P0/P1 lgkm+barriers].
// vmcnt(4) once per tile at P3: 12 outstanding -> retire 8 (all of tile t+1), keep
// B(t+2)'s 4. Swizzle (128B rows): slot' = (kk*4+g)^(r&7); inverse on staging src col.
template <int EPI>
__global__ __launch_bounds__(512) void gemm256(
    const unsigned short* __restrict__ A, const unsigned short* __restrict__ B,
    void* __restrict__ Cv, const float* __restrict__ bias,
    int lda, int ldb, int N, int Kslice) {
    extern __shared__ char smem[];  // 2 x 64KB
    const int t = threadIdx.x;

    // XCD-chunked bijective block swizzle (all grid totals divisible by 8)
    const int gx = gridDim.x, gy = gridDim.y;
    const int total = gx * gy * gridDim.z;
    int flat = blockIdx.x + gx * (blockIdx.y + gy * blockIdx.z);
    flat = (flat & 7) * (total >> 3) + (flat >> 3);
    const int bx = flat % gx;
    const int byz = flat / gx;
    const int by = byz % gy;
    const int z = byz / gy;

    const int m0 = by * 256, n0 = bx * 256;
    const unsigned short* Ag = A + (size_t)z * Kslice;
    const unsigned short* Bg = B + (size_t)z * Kslice;
    const int NT = Kslice >> 6;  // BK=64

    // staging precompute: per half-tile, 2 chunks of 16B per thread
    size_t aoff[2], boff[2];
    int loff[2];
#pragma unroll
    for (int j = 0; j < 2; ++j) {
        int c = j * 512 + t;
        int srow = c >> 3;
        int scol = ((c & 7) ^ (srow & 7)) << 3;  // inverse-swizzled source col
        aoff[j] = (size_t)(m0 + srow) * lda + scol;
        boff[j] = (size_t)(n0 + srow) * ldb + scol;
        loff[j] = c << 4;
    }

    // fragment read precompute
    const int lane = t & 63, r = lane & 15, g = lane >> 4;
    const int wid = t >> 6, wm = wid >> 2, wn = wid & 3;
    int sA[2];
    sA[0] = ((0 + g) ^ (r & 7)) << 4;
    sA[1] = ((4 + g) ^ (r & 7)) << 4;
    const int aBase = wm * 16384 + r * 128;
    const int bBase = 32768 + (wn >> 1) * 16384 + ((wn & 1) * 64 + r) * 128;

#define STAGE_A(base, h, kt)                                                  \
    do {                                                                      \
        _Pragma("unroll") for (int j = 0; j < 2; ++j)                         \
            gload_lds16(Ag + aoff[j] + (size_t)(h) * 128 * lda +              \
                            (size_t)(kt) * 64,                                \
                        smem + (base) + (h) * 16384 + loff[j]);               \
    } while (0)
#define STAGE_B(base, h, kt)                                                  \
    do {                                                                      \
        _Pragma("unroll") for (int j = 0; j < 2; ++j)                         \
            gload_lds16(Bg + boff[j] + (size_t)(h) * 128 * ldb +              \
                            (size_t)(kt) * 64,                                \
                        smem + (base) + 32768 + (h) * 16384 + loff[j]);       \
    } while (0)

#define RD_AF(dbase, qm)                                                      \
    _Pragma("unroll") for (int mi = 0; mi < 4; ++mi)                          \
        _Pragma("unroll") for (int kk = 0; kk < 2; ++kk)                      \
            af[mi][kk] = *(const bf16x8*)(smem + (dbase) + aBase +            \
                                          ((qm) * 64 + mi * 16) * 128 + sA[kk]);
#define RD_BF(dbase, qn, BF)                                                  \
    _Pragma("unroll") for (int ni = 0; ni < 2; ++ni)                          \
        _Pragma("unroll") for (int kk = 0; kk < 2; ++kk)                      \
            BF[ni][kk] = *(const bf16x8*)(smem + (dbase) + bBase +            \
                                          ((qn) * 32 + ni * 16) * 128 + sA[kk]);
#define MM(qm, qn, BF)                                                        \
    __builtin_amdgcn_s_setprio(1);                                            \
    _Pragma("unroll") for (int mi = 0; mi < 4; ++mi)                          \
        _Pragma("unroll") for (int ni = 0; ni < 2; ++ni)                      \
            _Pragma("unroll") for (int kk = 0; kk < 2; ++kk)                  \
                acc[(qm) * 4 + mi][(qn) * 2 + ni] =                           \
                    __builtin_amdgcn_mfma_f32_16x16x32_bf16(                  \
                        af[mi][kk], BF[ni][kk],                               \
                        acc[(qm) * 4 + mi][(qn) * 2 + ni], 0, 0, 0);          \
    __builtin_amdgcn_s_setprio(0);

    f32x4 acc[8][4] = {};
    bf16x8 af[4][2], bf0[2][2], bf1[2][2];

    // prologue: tile0 (4 halves) + B halves of tile1; retire tile0 only
    STAGE_A(0, 0, 0);
    STAGE_A(0, 1, 0);
    STAGE_B(0, 0, 0);
    STAGE_B(0, 1, 0);
    if (1 < NT) {
        STAGE_B(65536, 0, 1);
        STAGE_B(65536, 1, 1);
        VMCNT4;
    } else {
        VMCNT0;
    }
    BAR;

    for (int kt = 0; kt < NT; ++kt) {
        const int dbase = (kt & 1) * 65536;
        const int nbase = dbase ^ 65536;
        // ---- P0: (m0,n0); stage A0(t+1) ----
        RD_AF(dbase, 0);
        RD_BF(dbase, 0, bf0);
        if (kt + 1 < NT) STAGE_A(nbase, 0, kt + 1);
        SCHED0;
        BAR;
        LGKM0S;
        MM(0, 0, bf0);
        BAR;
        // ---- P1: (m0,n1); stage A1(t+1) ----
        RD_BF(dbase, 1, bf1);
        if (kt + 1 < NT) STAGE_A(nbase, 1, kt + 1);
        SCHED0;
        BAR;
        LGKM0S;
        MM(0, 1, bf1);
        BAR;
        // ---- P2: (m1,n0); stage B0(t+2) into cur (safe: cur B reads retired) ----
        RD_AF(dbase, 1);
        if (kt + 2 < NT) STAGE_B(dbase, 0, kt + 2);
        SCHED0;
        BAR;
        LGKM0S;
        MM(1, 0, bf0);
        BAR;
        // ---- P3: (m1,n1); stage B1(t+2); counted vmcnt ----
        if (kt + 2 < NT) {
            STAGE_B(dbase, 1, kt + 2);
            VMCNT4;
        } else {
            VMCNT0;
        }
        SCHED0;
        BAR;
        SCHED0;
        MM(1, 1, bf1);
        BAR;
    }

    // epilogue: C-layout col=lane&15, row=(lane>>4)*4+j (verified mapping)
    const int crow0 = m0 + wm * 128 + g * 4;
    const int ccol0 = n0 + wn * 64 + r;
    float* Cp = (float*)Cv + (size_t)gridDim.y * 256 * N * z;
#pragma unroll
    for (int mi = 0; mi < 8; ++mi) {
#pragma unroll
        for (int ni = 0; ni < 4; ++ni) {
            int col = ccol0 + ni * 16;
            float bval = (EPI == 2) ? bias[col] : 0.f;
#pragma unroll
            for (int j = 0; j < 4; ++j) {
                int row = crow0 + mi * 16 + j;
                float v = acc[mi][ni][j];
                if (EPI == 0) {
                    ((unsigned short*)Cv)[(size_t)row * N + col] = f2bf(v);
                } else if (EPI == 1) {
                    Cp[(size_t)row * N + col] = v;
                } else {
                    v = fmaxf(v + bval, 0.f);
                    ((unsigned short*)Cv)[(size_t)row * N + col] = f2bf(v);
                }
            }
        }
    }
#undef STAGE_A
#undef STAGE_B
#undef RD_AF
#undef RD_BF
#undef MM
}

// ---------- fp32 -> bf16 convert (x) ----------
__global__ __launch_bounds__(256) void cvt_kernel(
    const float* __restrict__ in, unsigned short* __restrict__ out, int n4) {
    int idx = blockIdx.x * 256 + threadIdx.x;
    if (idx >= n4) return;
    float4 v = *(const float4*)(in + (size_t)idx * 4);
    ushort4 u = make_ushort4(f2bf(v.x), f2bf(v.y), f2bf(v.z), f2bf(v.w));
    *(ushort4*)(out + (size_t)idx * 4) = u;
}

// ---------- fused weight convert (all 6 weight matrices, one launch) ----------
__global__ __launch_bounds__(256) void wcvt_kernel(
    const float* __restrict__ Wq, const float* __restrict__ Wk,
    const float* __restrict__ Wv, const float* __restrict__ Wo,
    const float* __restrict__ W1, const float* __restrict__ W2,
    unsigned short* __restrict__ Wqkvbf, unsigned short* __restrict__ Wobf,
    unsigned short* __restrict__ W1bf, unsigned short* __restrict__ W2bf) {
    int idx = blockIdx.x * 256 + threadIdx.x;  // vec4 units; total 3145728
    const float* src;
    unsigned short* dst;
    if (idx < 786432) {  // Wq|Wk|Wv -> contiguous Wqkvbf
        dst = Wqkvbf + (size_t)idx * 4;
        src = (idx < 262144)   ? Wq + (size_t)idx * 4
              : (idx < 524288) ? Wk + (size_t)(idx - 262144) * 4
                               : Wv + (size_t)(idx - 524288) * 4;
    } else if (idx < 1048576) {
        src = Wo + (size_t)(idx - 786432) * 4;
        dst = Wobf + (size_t)(idx - 786432) * 4;
    } else if (idx < 2097152) {
        src = W1 + (size_t)(idx - 1048576) * 4;
        dst = W1bf + (size_t)(idx - 1048576) * 4;
    } else {
        src = W2 + (size_t)(idx - 2097152) * 4;
        dst = W2bf + (size_t)(idx - 2097152) * 4;
    }
    float4 v = *(const float4*)src;
    ushort4 u = make_ushort4(f2bf(v.x), f2bf(v.y), f2bf(v.z), f2bf(v.w));
    *(ushort4*)dst = u;
}

// ---------- energy[n,s,p=i*16+j] = (1/8) * dot64(Q[n,s,i], K[n,s,j]) ----------
__global__ __launch_bounds__(256) void energy_kernel(
    const unsigned short* __restrict__ QKV, float* __restrict__ E) {
    __shared__ __attribute__((aligned(16))) unsigned short Qs[8 * 1024];
    __shared__ __attribute__((aligned(16))) unsigned short Ks[8 * 1024];
    const int tid = threadIdx.x;
    const int n = blockIdx.y;
    const int s0 = blockIdx.x * 8;
#pragma unroll
    for (int c = 0; c < 4; ++c) {
        int e = c * 2048 + tid * 8;
        int row = e >> 10, col = e & 1023;
        int jj = col >> 6, db = (col >> 3) & 7;
        int sw = jj * 64 + (((db + jj) & 7) << 3);
        size_t gbase = (size_t)(n * 2048 + s0 + row) * 3072;
        *(us8*)(Qs + row * 1024 + sw) = *(const us8*)(QKV + gbase + col);
        *(us8*)(Ks + row * 1024 + sw) = *(const us8*)(QKV + gbase + 1024 + col);
    }
    __syncthreads();
    const int i = tid >> 4, j = tid & 15;
#pragma unroll
    for (int s = 0; s < 8; ++s) {
        float acc = 0.f;
#pragma unroll
        for (int d8 = 0; d8 < 8; ++d8) {
            us8 q = *(const us8*)(Qs + s * 1024 + i * 64 + (((d8 + i) & 7) << 3));
            us8 k = *(const us8*)(Ks + s * 1024 + j * 64 + (((d8 + j) & 7) << 3));
#pragma unroll
            for (int t = 0; t < 8; ++t) acc += bf2f(q[t]) * bf2f(k[t]);
        }
        E[(size_t)(n * 2048 + s0 + s) * 256 + tid] = acc * 0.125f;
    }
}

// ---------- softmax-over-s stats ----------
__global__ __launch_bounds__(256) void smax_part(
    const float* __restrict__ E, float* __restrict__ Mp, float* __restrict__ Zp) {
    const int p = threadIdx.x, n = blockIdx.y, sc = blockIdx.x;
    float m = -1e30f, z = 0.f;
    const float* base = E + ((size_t)n * 2048 + sc * 32) * 256 + p;
    for (int s = 0; s < 32; ++s) {
        float e = base[(size_t)s * 256];
        float mn = fmaxf(m, e);
        z = z * __expf(m - mn) + __expf(e - mn);
        m = mn;
    }
    int idx = (n * 64 + sc) * 256 + p;
    Mp[idx] = m;
    Zp[idx] = z;
}

__global__ __launch_bounds__(256) void smax_fin(
    const float* __restrict__ Mp, const float* __restrict__ Zp,
    float* __restrict__ Mf, float* __restrict__ RZf) {
    const int p = threadIdx.x, n = blockIdx.x;
    float m = -1e30f;
    for (int c = 0; c < 64; ++c) m = fmaxf(m, Mp[(n * 64 + c) * 256 + p]);
    float z = 0.f;
    for (int c = 0; c < 64; ++c)
        z += Zp[(n * 64 + c) * 256 + p] * __expf(Mp[(n * 64 + c) * 256 + p] - m);
    Mf[n * 256 + p] = m;
    RZf[n * 256 + p] = 1.f / z;
}

// ---------- attn_src[n, h*128+s/16, (s%16)*64+d] = A[n,h,s] * Vs[n,s,d] ----------
__global__ __launch_bounds__(256) void attnsrc_kernel(
    const unsigned short* __restrict__ QKV, const float* __restrict__ E,
    const float* __restrict__ Mf, const float* __restrict__ RZf,
    unsigned short* __restrict__ ASRC) {
    const int lane = threadIdx.x & 63;
    const int widx = blockIdx.x * 4 + (threadIdx.x >> 6);
    const int n = widx >> 11, s = widx & 2047;
    float vs = 0.f;
    const unsigned short* vrow = QKV + (size_t)(n * 2048 + s) * 3072 + 2048;
#pragma unroll
    for (int h = 0; h < 16; ++h) vs += bf2f(vrow[h * 64 + lane]);
    float aval = 0.f;
    if (lane < 16) {
        const float* erow = E + (size_t)(n * 2048 + s) * 256 + lane * 16;
        const float* mrow = Mf + n * 256 + lane * 16;
        const float* zrow = RZf + n * 256 + lane * 16;
#pragma unroll
        for (int j = 0; j < 16; ++j)
            aval += __expf(erow[j] - mrow[j]) * zrow[j];
    }
#pragma unroll
    for (int h = 0; h < 16; ++h) {
        float ah = __shfl(aval, h, 64);
        size_t row = (size_t)n * 2048 + h * 128 + (s >> 4);
        ASRC[row * 1024 + (s & 15) * 64 + lane] = f2bf(ah * vs);
    }
}

// ---------- LayerNorm(lin [+ lin2] + bias + resid_bf16) * w + b ----------
__global__ __launch_bounds__(256) void ln_kernel(
    const float* __restrict__ lin, const float* __restrict__ lin2,
    const float* __restrict__ bias, const unsigned short* __restrict__ residbf,
    const float* __restrict__ w, const float* __restrict__ b,
    unsigned short* __restrict__ obf, float* __restrict__ of) {
    __shared__ float sm[16];
    const int row = blockIdx.x, c = threadIdx.x * 4;
    const size_t off = (size_t)row * 1024 + c;
    float4 v = *(const float4*)(lin + off);
    float4 bs = *(const float4*)(bias + c);
    ushort4 rx = *(const ushort4*)(residbf + off);
    float t0 = v.x + bs.x + bf2f(rx.x);
    float t1 = v.y + bs.y + bf2f(rx.y);
    float t2 = v.z + bs.z + bf2f(rx.z);
    float t3 = v.w + bs.w + bf2f(rx.w);
    if (lin2) {
        float4 v2 = *(const float4*)(lin2 + off);
        t0 += v2.x; t1 += v2.y; t2 += v2.z; t3 += v2.w;
    }
    float s = t0 + t1 + t2 + t3;
    float ss = t0 * t0 + t1 * t1 + t2 * t2 + t3 * t3;
#pragma unroll
    for (int o = 32; o > 0; o >>= 1) {
        s += __shfl_down(s, o, 64);
        ss += __shfl_down(ss, o, 64);
    }
    const int wv = threadIdx.x >> 6, ln = threadIdx.x & 63;
    if (ln == 0) {
        sm[wv] = s;
        sm[8 + wv] = ss;
    }
    __syncthreads();
    if (threadIdx.x == 0) {
        sm[4] = sm[0] + sm[1] + sm[2] + sm[3];
        sm[12] = sm[8] + sm[9] + sm[10] + sm[11];
    }
    __syncthreads();
    s = sm[4];
    ss = sm[12];
    float mean = s * (1.f / 1024.f);
    float var = ss * (1.f / 1024.f) - mean * mean;
    float rstd = rsqrtf(var + 1e-5f);
    float4 wv4 = *(const float4*)(w + c);
    float4 bv4 = *(const float4*)(b + c);
    float o0 = (t0 - mean) * rstd * wv4.x + bv4.x;
    float o1 = (t1 - mean) * rstd * wv4.y + bv4.y;
    float o2 = (t2 - mean) * rstd * wv4.z + bv4.z;
    float o3 = (t3 - mean) * rstd * wv4.w + bv4.w;
    if (of) {
        float4 o = make_float4(o0, o1, o2, o3);
        *(float4*)(of + off) = o;
    }
    if (obf) {
        ushort4 u = make_ushort4(f2bf(o0), f2bf(o1), f2bf(o2), f2bf(o3));
        *(ushort4*)(obf + off) = u;
    }
}

// ---------- launch ----------
extern "C" void kernel_launch(void* const* d_in, const int* in_sizes, int n_in,
                              void* d_out, int out_size, void* d_ws, size_t ws_size,
                              hipStream_t stream) {
    const float* x = (const float*)d_in[0];
    const float* Wq = (const float*)d_in[1];
    const float* Wk = (const float*)d_in[2];
    const float* Wv = (const float*)d_in[3];
    const float* Wo = (const float*)d_in[4];
    const float* bo = (const float*)d_in[5];
    const float* ln1w = (const float*)d_in[6];
    const float* ln1b = (const float*)d_in[7];
    const float* ln2w = (const float*)d_in[8];
    const float* ln2b = (const float*)d_in[9];
    const float* W1 = (const float*)d_in[10];
    const float* bf1 = (const float*)d_in[11];
    const float* W2 = (const float*)d_in[12];
    const float* bf2 = (const float*)d_in[13];

    char* ws = (char*)d_ws;
    const size_t MB = 1u << 20;
    const size_t KB = 1u << 10;
    // region map (MB), lifetimes annotated (peak 192 MB, proven layout):
    unsigned short* W1bf = (unsigned short*)(ws + 0);          // [1..8]
    unsigned short* W2bf = (unsigned short*)(ws + 8 * MB);     // [1..9]
    unsigned short* Wobf = (unsigned short*)(ws + 16 * MB);    // [1..6]
    unsigned short* Wqkvbf = (unsigned short*)(ws + 18 * MB);  // [1..2]
    float* Mp = (float*)(ws + 24 * MB);                        // [4] 256KB
    float* Zp = (float*)(ws + 24 * MB + 256 * KB);             // [4] 256KB
    float* Mfin = (float*)(ws + 24 * MB + 512 * KB);           // [4..5]
    float* RZfin = (float*)(ws + 24 * MB + 528 * KB);          // [4..5]
    float* EN = (float*)(ws + 32 * MB);                        // [3..5] 8MB (free gap)
    unsigned short* ASRC = (unsigned short*)(ws + 48 * MB);    // [5..6]
    unsigned short* x1bf = (unsigned short*)(ws + 48 * MB);    // [7..10] (over ASRC)
    float* AL = (float*)(ws + 64 * MB);                        // [6..7] (z0:64-96, z1:96-128)
    unsigned short* H1 = (unsigned short*)(ws + 64 * MB);      // [8..9] (over AL)
    unsigned short* QKV = (unsigned short*)(ws + 128 * MB);    // [2..5]
    float* FF = (float*)(ws + 128 * MB);                       // [9..10] (over QKV)
    unsigned short* xbf = (unsigned short*)(ws + 176 * MB);    // [1..7]

    // allow 128 KiB dynamic LDS (idempotent; safe under graph capture)
    auto k0 = gemm256<0>; auto k1 = gemm256<1>; auto k2 = gemm256<2>;
    (void)hipFuncSetAttribute((const void*)k0, hipFuncAttributeMaxDynamicSharedMemorySize, 131072);
    (void)hipFuncSetAttribute((const void*)k1, hipFuncAttributeMaxDynamicSharedMemorySize, 131072);
    (void)hipFuncSetAttribute((const void*)k2, hipFuncAttributeMaxDynamicSharedMemorySize, 131072);

    // 1. conversions (2 launches)
    cvt_kernel<<<dim3(8192), 256, 0, stream>>>(x, xbf, 2097152);
    wcvt_kernel<<<dim3(12288), 256, 0, stream>>>(Wq, Wk, Wv, Wo, W1, W2,
                                                 Wqkvbf, Wobf, W1bf, W2bf);

    // 2. QKV = xbf @ [Wq;Wk;Wv]^T  (8192 x 3072, bf16)
    gemm256<0><<<dim3(12, 32, 1), 512, 131072, stream>>>(
        xbf, Wqkvbf, QKV, nullptr, 1024, 1024, 3072, 1024);
    // 3-5. attention (cheap part)
    energy_kernel<<<dim3(256, 4), 256, 0, stream>>>(QKV, EN);
    smax_part<<<dim3(64, 4), 256, 0, stream>>>(EN, Mp, Zp);
    smax_fin<<<dim3(4), 256, 0, stream>>>(Mp, Zp, Mfin, RZfin);
    attnsrc_kernel<<<dim3(2048), 256, 0, stream>>>(QKV, EN, Mfin, RZfin, ASRC);
    // 6. attn_lin = ASRC @ Wo^T, split-K=2 fp32 partials
    gemm256<1><<<dim3(4, 32, 2), 512, 131072, stream>>>(
        ASRC, Wobf, AL, nullptr, 1024, 1024, 1024, 512);
    // 7. x1 = LN1(AL0 + AL1 + bo + xbf) -> bf16 only
    ln_kernel<<<dim3(8192), 256, 0, stream>>>(
        AL, AL + (size_t)8192 * 1024, bo, xbf, ln1w, ln1b, x1bf, nullptr);
    // 8. H1 = relu(x1 @ W1^T + bf1)
    gemm256<2><<<dim3(16, 32, 1), 512, 131072, stream>>>(
        x1bf, W1bf, H1, bf1, 1024, 1024, 4096, 1024);
    // 9. ff = H1 @ W2^T, split-K=2 fp32 partials
    gemm256<1><<<dim3(4, 32, 2), 512, 131072, stream>>>(
        H1, W2bf, FF, nullptr, 4096, 4096, 1024, 2048);
    // 10. out = LN2(ff0 + ff1 + bf2 + x1bf)
    ln_kernel<<<dim3(8192), 256, 0, stream>>>(
        FF, FF + (size_t)8192 * 1024, bf2, x1bf, ln2w, ln2b, nullptr, (float*)d_out);
}